// Round 1
// baseline (718.262 us; speedup 1.0000x reference)
//
#include <hip/hip_runtime.h>
#include <hip/hip_bf16.h>
#include <stdint.h>

#define NTOK 4096
#define DIM  1024
#define TOPK 128
#define GB   32      // greedy blocks (empirical optimum)
#define GT   128     // threads per greedy block; GB*GT == NTOK
#define NEGM -1e30f

typedef __attribute__((ext_vector_type(8))) short bf16x8;
typedef __attribute__((ext_vector_type(4))) float f32x4;

// ---------------------------------------------------------------------------
// k_prep: rel[n] = ((-a[n]) - min(-a) + 1e-6) / (max(-a) - min(-a))
// ---------------------------------------------------------------------------
__global__ __launch_bounds__(1024) void k_prep(const float* __restrict__ attn,
                                               float* __restrict__ rel) {
  __shared__ float smx[16], smn[16];
  int tid = threadIdx.x;
  float mx = -3.4e38f, mn = 3.4e38f;
  for (int n = tid; n < NTOK; n += 1024) {
    float a = attn[n];
    mx = fmaxf(mx, a); mn = fminf(mn, a);
  }
  for (int o = 32; o >= 1; o >>= 1) {
    mx = fmaxf(mx, __shfl_down(mx, o, 64));
    mn = fminf(mn, __shfl_down(mn, o, 64));
  }
  if ((tid & 63) == 0) { smx[tid >> 6] = mx; smn[tid >> 6] = mn; }
  __syncthreads();
  if (tid == 0) {
    float MX = smx[0], MN = smn[0];
    for (int w = 1; w < 16; ++w) { MX = fmaxf(MX, smx[w]); MN = fminf(MN, smn[w]); }
    smx[0] = MX; smn[0] = MN;
  }
  __syncthreads();
  float amax = smx[0], amin = smn[0];
  float rmin  = -amax;
  float range = (-amin) - rmin;
  for (int n = tid; n < NTOK; n += 1024) {
    float r = -attn[n];
    rel[n] = ((r - rmin) + 1e-6f) / range;
  }
}

// ---------------------------------------------------------------------------
// k_norm: xn = x/||x||, then EXACT bf16 split: hi=bf16(xn), lo=bf16(xn-hi).
// ---------------------------------------------------------------------------
__global__ __launch_bounds__(256) void k_norm(const float* __restrict__ x,
                                              __hip_bfloat16* __restrict__ H,
                                              __hip_bfloat16* __restrict__ L) {
  __shared__ float ps[4];
  int row = blockIdx.x, tid = threadIdx.x;
  const float4* xr = (const float4*)(x + (size_t)row * DIM);
  float4 v = xr[tid];
  float s = v.x * v.x + v.y * v.y + v.z * v.z + v.w * v.w;
  for (int o = 32; o >= 1; o >>= 1) s += __shfl_down(s, o, 64);
  if ((tid & 63) == 0) ps[tid >> 6] = s;
  __syncthreads();
  if (tid == 0) ps[0] = ps[0] + ps[1] + ps[2] + ps[3];
  __syncthreads();
  float nrm = sqrtf(ps[0]);
  float xf[4] = {v.x / nrm, v.y / nrm, v.z / nrm, v.w / nrm};
  __hip_bfloat16 hh[4], ll[4];
#pragma unroll
  for (int e = 0; e < 4; ++e) {
    hh[e] = __float2bfloat16(xf[e]);
    float lof = xf[e] - __bfloat162float(hh[e]);
    ll[e] = __float2bfloat16(lof);
  }
  *(short4*)(H + (size_t)row * DIM + tid * 4) = *(short4*)hh;
  *(short4*)(L + (size_t)row * DIM + tid * 4) = *(short4*)ll;
}

// ---------------------------------------------------------------------------
// k_gemm (MFMA split-bf16, FUSED-PHASE staging) — unchanged from r15.
// ---------------------------------------------------------------------------
__global__ __launch_bounds__(256) void k_gemm(const __hip_bfloat16* __restrict__ H,
                                              const __hip_bfloat16* __restrict__ L,
                                              const float* __restrict__ rel,
                                              float* __restrict__ ker) {
  int bi = blockIdx.y, bj = blockIdx.x;
  if (bi > bj) return;
  __shared__ __align__(16) char smem[65536];  // buf p at p*32768: AH,AL,BH,BL
  int tid = threadIdx.x;
  int lane = tid & 63, wid = tid >> 6;
  int wr = wid >> 1, wc = wid & 1;
  int lm = lane & 15, quad = lane >> 4;
  int lrow = lane >> 2;                       // 0..15 within a 16-row group
  int kcf  = (lane & 3) ^ ((lane >> 2) & 3);  // global chunk to fetch (swizzle)
  const __hip_bfloat16* M[4] = {
      H + (size_t)(bi * 128) * DIM, L + (size_t)(bi * 128) * DIM,   // A_H, A_L
      H + (size_t)(bj * 128) * DIM, L + (size_t)(bj * 128) * DIM};  // B_H, B_L
  f32x4 acc[4][4];
#pragma unroll
  for (int r = 0; r < 4; ++r)
#pragma unroll
    for (int c = 0; c < 4; ++c) acc[r][c] = (f32x4){0.f, 0.f, 0.f, 0.f};

#define ISSUE_STAGE(s, pbuf)                                                   \
  {                                                                            \
    int kk = (s) * 32;                                                         \
    char* base = smem + (pbuf) * 32768;                                        \
    _Pragma("unroll")                                                          \
    for (int m = 0; m < 4; ++m) {                                              \
      _Pragma("unroll")                                                        \
      for (int q = 0; q < 2; ++q) {                                            \
        int r0 = wid * 32 + q * 16;                                            \
        const __hip_bfloat16* g =                                              \
            M[m] + (size_t)(r0 + lrow) * DIM + kk + kcf * 8;                   \
        __builtin_amdgcn_global_load_lds(                                      \
            (const __attribute__((address_space(1))) void*)g,                  \
            (__attribute__((address_space(3))) void*)(base + m * 8192 +        \
                                                      r0 * 64),                \
            16, 0, 0);                                                         \
      }                                                                        \
    }                                                                          \
  }

  ISSUE_STAGE(0, 0);
  int p = 0;
  for (int s = 0; s < 32; ++s) {              // K = 32 stages x 32
    __syncthreads();   // stage-s loads landed (flew during prev compute)
    if (s + 1 < 32) ISSUE_STAGE(s + 1, 1 - p);
    const char* b = smem + p * 32768;
    bf16x8 aH[4], aL[4], bH[4], bL[4];
#pragma unroll
    for (int r = 0; r < 4; ++r) {
      int row = wr * 64 + r * 16 + lm;        // row&3 == lm&3
      int off = row * 64 + ((quad ^ (lm & 3)) * 16);
      aH[r] = *(const bf16x8*)(b + off);
      aL[r] = *(const bf16x8*)(b + 8192 + off);
    }
#pragma unroll
    for (int c = 0; c < 4; ++c) {
      int row = wc * 64 + c * 16 + lm;
      int off = row * 64 + ((quad ^ (lm & 3)) * 16);
      bH[c] = *(const bf16x8*)(b + 16384 + off);
      bL[c] = *(const bf16x8*)(b + 24576 + off);
    }
#pragma unroll
    for (int r = 0; r < 4; ++r)
#pragma unroll
      for (int c = 0; c < 4; ++c) {
        acc[r][c] = __builtin_amdgcn_mfma_f32_16x16x32_bf16(aH[r], bH[c],
                                                            acc[r][c], 0, 0, 0);
        acc[r][c] = __builtin_amdgcn_mfma_f32_16x16x32_bf16(aH[r], bL[c],
                                                            acc[r][c], 0, 0, 0);
        acc[r][c] = __builtin_amdgcn_mfma_f32_16x16x32_bf16(aL[r], bH[c],
                                                            acc[r][c], 0, 0, 0);
        acc[r][c] = __builtin_amdgcn_mfma_f32_16x16x32_bf16(aL[r], bL[c],
                                                            acc[r][c], 0, 0, 0);
      }
    p ^= 1;
  }
#undef ISSUE_STAGE
  // ---- epilogue: rel scaling, reference op order (unchanged)
  float rr[16], rc[4];
#pragma unroll
  for (int r = 0; r < 4; ++r)
#pragma unroll
    for (int e = 0; e < 4; ++e)
      rr[r * 4 + e] = rel[bi * 128 + wr * 64 + r * 16 + quad * 4 + e];
#pragma unroll
  for (int c = 0; c < 4; ++c) rc[c] = rel[bj * 128 + wc * 64 + c * 16 + lm];
#pragma unroll
  for (int r = 0; r < 4; ++r) {
    int grow = bi * 128 + wr * 64 + r * 16 + quad * 4;
#pragma unroll
    for (int c = 0; c < 4; ++c) {
      int gcol = bj * 128 + wc * 64 + c * 16 + lm;
#pragma unroll
      for (int e = 0; e < 4; ++e)
        ker[(size_t)(grow + e) * NTOK + gcol] =
            (acc[r][c][e] * rr[r * 4 + e]) * rc[c];
    }
  }
  if (bi != bj) {
    __syncthreads();
    float* Tw = (float*)(smem + wid * 4672);
#pragma unroll
    for (int c = 0; c < 4; ++c) {
#pragma unroll
      for (int r = 0; r < 4; ++r)
#pragma unroll
        for (int e = 0; e < 4; ++e)
          Tw[lm * 73 + r * 16 + quad * 4 + e] =
              (acc[r][c][e] * rc[c]) * rr[r * 4 + e];
      __syncthreads();
      int cc2 = lane >> 2, seg = lane & 3;
      float* dst = &ker[(size_t)(bj * 128 + wc * 64 + c * 16 + cc2) * NTOK +
                        bi * 128 + wr * 64 + seg * 16];
#pragma unroll
      for (int e = 0; e < 4; ++e)
        *(float4*)&dst[e * 4] = *(const float4*)&Tw[cc2 * 73 + seg * 16 + e * 4];
      __syncthreads();
    }
  }
}

// ---------------------------------------------------------------------------
// k_greedy v2 — bit-exact restructure of the r11..r15 greedy:
//   (1) cisT layout flipped to [t][token]: the per-iteration eis store is now
//       one coalesced 512B row-slice per block (8 cache lines) instead of a
//       128-line scatter -> the vmcnt(0) drain at B1 (which sits between the
//       local argmax and the release slot-store, i.e. ON the serial chain)
//       collapses.  Winner-column read becomes a 32-lane strided gather (one
//       parallel L3 round, same latency class as before).
//   (2) kj prefetch: right after wave0's cross-block reduce (j known) and the
//       acquire fence, lanes 0-31 fetch this block's 128-float slice of
//       ker[j] into LDS *concurrently* with lanes 32-63 gathering the history
//       column.  After B2, kj is an LDS read -> the dependent ~0.4us global
//       load is folded into the same L3 round-trip as the colbuf gather.
// Same values, same summation order -> selection (and absmax=0.0) unchanged.
// ---------------------------------------------------------------------------
__global__ __launch_bounds__(GT) void k_greedy(const float* __restrict__ ker,
                                               const float* __restrict__ feat,
                                               float* __restrict__ out,
                                               float* __restrict__ cisT,
                                               unsigned long long* __restrict__ slots) {
  __shared__ __align__(16) float histT[GT][132];   // [token][t], 67.6 KB
  __shared__ __align__(16) float colbuf[TOPK];
  __shared__ __align__(16) float kjbuf[GT];
  __shared__ unsigned long long redw[GT / 64];
  __shared__ unsigned long long bwS;
  __shared__ int selj[TOPK];
  int tid = threadIdx.x;
  int lane = tid & 63, wid = tid >> 6;
  int blk = blockIdx.x;
  int n = blk * GT + tid;
  float di2s = ker[(size_t)n * NTOK + n];
#pragma unroll
  for (int t = 0; t < TOPK; t += 4)
    *(float4*)&histT[tid][t] = (float4){0.f, 0.f, 0.f, 0.f};

  for (int i = 0; i < TOPK; ++i) {
    unsigned u = __float_as_uint(di2s);
    unsigned key = (u & 0x80000000u) ? ~u : (u | 0x80000000u);
    unsigned long long pk =
        ((unsigned long long)key << 32) | (unsigned)(NTOK - 1 - n);
    for (int o = 32; o >= 1; o >>= 1) {
      unsigned long long q = __shfl_down(pk, o, 64);
      if (q > pk) pk = q;
    }
    if (lane == 0) redw[wid] = pk;
    __syncthreads();   // B1: orders redw + drains iter-(i-1) cisT row store
    if (tid == 0) {
      unsigned long long m = redw[0];
      if (redw[1] > m) m = redw[1];
      __hip_atomic_store(&slots[((size_t)i * GB + blk) * 8], m,
                         __ATOMIC_RELEASE, __HIP_MEMORY_SCOPE_AGENT);
    }
    if (wid == 0) {
      unsigned long long v = 0;
      if (lane < GB) {
        do {
          v = __hip_atomic_load(&slots[((size_t)i * GB + lane) * 8],
                                __ATOMIC_RELAXED, __HIP_MEMORY_SCOPE_AGENT);
        } while (v == 0);
      }
      unsigned long long b1 = v;
      for (int o = 32; o >= 1; o >>= 1) {
        unsigned long long q = __shfl_down(b1, o, 64);
        if (q > b1) b1 = q;
      }
      b1 = __shfl(b1, 0, 64);
      __builtin_amdgcn_fence(__ATOMIC_ACQUIRE, "agent");
      int jw = NTOK - 1 - (int)(b1 & 0xffffffffu);
      if (lane < 32) {
        // this block's 128-float slice of row ker[jw] -> LDS (plain cached
        // loads: ker written by a prior kernel, coherent at launch boundary)
        *(float4*)&kjbuf[lane * 4] =
            *(const float4*)(ker + (size_t)jw * NTOK + (size_t)blk * GT +
                             lane * 4);
      } else {
        // winner history column: cisT[t][jw], t = 0..127 (t>=i is unused
        // garbage).  Agent-relaxed atomic loads (bypass L1/L2 -> no stale
        // lines), acquire-fenced against the slot poll above.
        int le = lane - 32;
#pragma unroll
        for (int k = 0; k < 4; ++k) {
          int t = le * 4 + k;
          colbuf[t] = __hip_atomic_load(&cisT[(size_t)t * NTOK + jw],
                                        __ATOMIC_RELAXED,
                                        __HIP_MEMORY_SCOPE_AGENT);
        }
      }
      if (lane == 0) bwS = b1;
    }
    __syncthreads();   // B2: colbuf + kjbuf + bwS published block-wide
    unsigned long long b1 = bwS;
    int j = NTOK - 1 - (int)(b1 & 0xffffffffu);
    unsigned kw = (unsigned)(b1 >> 32);
    unsigned du = (kw & 0x80000000u) ? (kw & 0x7fffffffu) : ~kw;
    float sd = sqrtf(__uint_as_float(du));
    if (tid == 0) selj[i] = j;
    float kj = kjbuf[tid];
    float proj = 0.f;
    for (int t = 0; t < i; t += 4) {
      float4 c4 = *(const float4*)&colbuf[t];
      float4 h4 = *(const float4*)&histT[tid][t];
      proj += c4.x * h4.x + c4.y * h4.y + c4.z * h4.z + c4.w * h4.w;
    }
    float eis = (kj - proj) / sd;
    // coalesced row store: cisT[i][n] (4B x 64 consecutive lanes = 4 lines/wave)
    __hip_atomic_store(&cisT[(size_t)i * NTOK + n], eis, __ATOMIC_RELAXED,
                       __HIP_MEMORY_SCOPE_AGENT);
    histT[tid][i] = eis;
    di2s -= eis * eis;
    if (n == j) di2s = NEGM;
  }
  __syncthreads();
  for (int k = blk; k < TOPK; k += GB) {
    int j = selj[k];
    const float4* src = (const float4*)(feat + (size_t)j * DIM);
    float4* dst = (float4*)(out + (size_t)k * DIM);
    dst[tid]       = src[tid];
    dst[tid + GT]  = src[tid + GT];
  }
}

// ---------------------------------------------------------------------------
// ws layout (bytes):
//   [0,262144)        slots: 128 iters x 32 blocks x 64B (zeroed each launch)
//   [262144,278528)   rel  : 4096 f32
//   [1MB, +8MB)       H    : 4096x1024 bf16
//   [1MB+8MB, +8MB)   L    : 4096x1024 bf16
//   [1MB+16MB, +2MB)  cisT : 128x4096 f32  (layout [t][token])
//   [1MB+20MB, +64MB) ker  : 4096x4096 f32
// total ~85 MB
// ---------------------------------------------------------------------------
extern "C" void kernel_launch(void* const* d_in, const int* in_sizes, int n_in,
                              void* d_out, int out_size, void* d_ws, size_t ws_size,
                              hipStream_t stream) {
  const float* feat = (const float*)d_in[0];
  const float* attn = (const float*)d_in[1];
  float* out = (float*)d_out;
  char* ws = (char*)d_ws;

  unsigned long long* slots = (unsigned long long*)ws;
  float* rel = (float*)(ws + 262144);
  __hip_bfloat16* H = (__hip_bfloat16*)(ws + (1 << 20));
  __hip_bfloat16* L = (__hip_bfloat16*)(ws + (1 << 20) + (8 << 20));
  float* cisT = (float*)(ws + (1 << 20) + (16 << 20));
  float* ker  = (float*)(ws + (1 << 20) + (16 << 20) + (4 << 20));

  hipMemsetAsync(d_ws, 0, 262144, stream);
  k_prep<<<1, 1024, 0, stream>>>(attn, rel);
  k_norm<<<NTOK, 256, 0, stream>>>(feat, H, L);
  k_gemm<<<dim3(32, 32), 256, 0, stream>>>(H, L, rel, ker);
  k_greedy<<<GB, GT, 0, stream>>>(ker, feat, out, cisT, slots);
}

// Round 2
// 636.181 us; speedup vs baseline: 1.1290x; 1.1290x over previous
//
#include <hip/hip_runtime.h>
#include <hip/hip_bf16.h>
#include <stdint.h>

#define NTOK 4096
#define DIM  1024
#define TOPK 128
#define GB   32      // greedy blocks (empirical optimum)
#define GT   128     // threads per greedy block; GB*GT == NTOK
#define NEGM -1e30f

typedef __attribute__((ext_vector_type(8))) short bf16x8;
typedef __attribute__((ext_vector_type(4))) float f32x4;

// ---------------------------------------------------------------------------
// k_prep: rel[n] = ((-a[n]) - min(-a) + 1e-6) / (max(-a) - min(-a))
// ---------------------------------------------------------------------------
__global__ __launch_bounds__(1024) void k_prep(const float* __restrict__ attn,
                                               float* __restrict__ rel) {
  __shared__ float smx[16], smn[16];
  int tid = threadIdx.x;
  float mx = -3.4e38f, mn = 3.4e38f;
  for (int n = tid; n < NTOK; n += 1024) {
    float a = attn[n];
    mx = fmaxf(mx, a); mn = fminf(mn, a);
  }
  for (int o = 32; o >= 1; o >>= 1) {
    mx = fmaxf(mx, __shfl_down(mx, o, 64));
    mn = fminf(mn, __shfl_down(mn, o, 64));
  }
  if ((tid & 63) == 0) { smx[tid >> 6] = mx; smn[tid >> 6] = mn; }
  __syncthreads();
  if (tid == 0) {
    float MX = smx[0], MN = smn[0];
    for (int w = 1; w < 16; ++w) { MX = fmaxf(MX, smx[w]); MN = fminf(MN, smn[w]); }
    smx[0] = MX; smn[0] = MN;
  }
  __syncthreads();
  float amax = smx[0], amin = smn[0];
  float rmin  = -amax;
  float range = (-amin) - rmin;
  for (int n = tid; n < NTOK; n += 1024) {
    float r = -attn[n];
    rel[n] = ((r - rmin) + 1e-6f) / range;
  }
}

// ---------------------------------------------------------------------------
// k_norm: xn = x/||x||, then EXACT bf16 split: hi=bf16(xn), lo=bf16(xn-hi).
// ---------------------------------------------------------------------------
__global__ __launch_bounds__(256) void k_norm(const float* __restrict__ x,
                                              __hip_bfloat16* __restrict__ H,
                                              __hip_bfloat16* __restrict__ L) {
  __shared__ float ps[4];
  int row = blockIdx.x, tid = threadIdx.x;
  const float4* xr = (const float4*)(x + (size_t)row * DIM);
  float4 v = xr[tid];
  float s = v.x * v.x + v.y * v.y + v.z * v.z + v.w * v.w;
  for (int o = 32; o >= 1; o >>= 1) s += __shfl_down(s, o, 64);
  if ((tid & 63) == 0) ps[tid >> 6] = s;
  __syncthreads();
  if (tid == 0) ps[0] = ps[0] + ps[1] + ps[2] + ps[3];
  __syncthreads();
  float nrm = sqrtf(ps[0]);
  float xf[4] = {v.x / nrm, v.y / nrm, v.z / nrm, v.w / nrm};
  __hip_bfloat16 hh[4], ll[4];
#pragma unroll
  for (int e = 0; e < 4; ++e) {
    hh[e] = __float2bfloat16(xf[e]);
    float lof = xf[e] - __bfloat162float(hh[e]);
    ll[e] = __float2bfloat16(lof);
  }
  *(short4*)(H + (size_t)row * DIM + tid * 4) = *(short4*)hh;
  *(short4*)(L + (size_t)row * DIM + tid * 4) = *(short4*)ll;
}

// ---------------------------------------------------------------------------
// k_gemm (MFMA split-bf16, FUSED-PHASE staging) — unchanged from r15.
// ---------------------------------------------------------------------------
__global__ __launch_bounds__(256) void k_gemm(const __hip_bfloat16* __restrict__ H,
                                              const __hip_bfloat16* __restrict__ L,
                                              const float* __restrict__ rel,
                                              float* __restrict__ ker) {
  int bi = blockIdx.y, bj = blockIdx.x;
  if (bi > bj) return;
  __shared__ __align__(16) char smem[65536];  // buf p at p*32768: AH,AL,BH,BL
  int tid = threadIdx.x;
  int lane = tid & 63, wid = tid >> 6;
  int wr = wid >> 1, wc = wid & 1;
  int lm = lane & 15, quad = lane >> 4;
  int lrow = lane >> 2;                       // 0..15 within a 16-row group
  int kcf  = (lane & 3) ^ ((lane >> 2) & 3);  // global chunk to fetch (swizzle)
  const __hip_bfloat16* M[4] = {
      H + (size_t)(bi * 128) * DIM, L + (size_t)(bi * 128) * DIM,   // A_H, A_L
      H + (size_t)(bj * 128) * DIM, L + (size_t)(bj * 128) * DIM};  // B_H, B_L
  f32x4 acc[4][4];
#pragma unroll
  for (int r = 0; r < 4; ++r)
#pragma unroll
    for (int c = 0; c < 4; ++c) acc[r][c] = (f32x4){0.f, 0.f, 0.f, 0.f};

#define ISSUE_STAGE(s, pbuf)                                                   \
  {                                                                            \
    int kk = (s) * 32;                                                         \
    char* base = smem + (pbuf) * 32768;                                        \
    _Pragma("unroll")                                                          \
    for (int m = 0; m < 4; ++m) {                                              \
      _Pragma("unroll")                                                        \
      for (int q = 0; q < 2; ++q) {                                            \
        int r0 = wid * 32 + q * 16;                                            \
        const __hip_bfloat16* g =                                              \
            M[m] + (size_t)(r0 + lrow) * DIM + kk + kcf * 8;                   \
        __builtin_amdgcn_global_load_lds(                                      \
            (const __attribute__((address_space(1))) void*)g,                  \
            (__attribute__((address_space(3))) void*)(base + m * 8192 +        \
                                                      r0 * 64),                \
            16, 0, 0);                                                         \
      }                                                                        \
    }                                                                          \
  }

  ISSUE_STAGE(0, 0);
  int p = 0;
  for (int s = 0; s < 32; ++s) {              // K = 32 stages x 32
    __syncthreads();   // stage-s loads landed (flew during prev compute)
    if (s + 1 < 32) ISSUE_STAGE(s + 1, 1 - p);
    const char* b = smem + p * 32768;
    bf16x8 aH[4], aL[4], bH[4], bL[4];
#pragma unroll
    for (int r = 0; r < 4; ++r) {
      int row = wr * 64 + r * 16 + lm;        // row&3 == lm&3
      int off = row * 64 + ((quad ^ (lm & 3)) * 16);
      aH[r] = *(const bf16x8*)(b + off);
      aL[r] = *(const bf16x8*)(b + 8192 + off);
    }
#pragma unroll
    for (int c = 0; c < 4; ++c) {
      int row = wc * 64 + c * 16 + lm;
      int off = row * 64 + ((quad ^ (lm & 3)) * 16);
      bH[c] = *(const bf16x8*)(b + 16384 + off);
      bL[c] = *(const bf16x8*)(b + 24576 + off);
    }
#pragma unroll
    for (int r = 0; r < 4; ++r)
#pragma unroll
      for (int c = 0; c < 4; ++c) {
        acc[r][c] = __builtin_amdgcn_mfma_f32_16x16x32_bf16(aH[r], bH[c],
                                                            acc[r][c], 0, 0, 0);
        acc[r][c] = __builtin_amdgcn_mfma_f32_16x16x32_bf16(aH[r], bL[c],
                                                            acc[r][c], 0, 0, 0);
        acc[r][c] = __builtin_amdgcn_mfma_f32_16x16x32_bf16(aL[r], bH[c],
                                                            acc[r][c], 0, 0, 0);
        acc[r][c] = __builtin_amdgcn_mfma_f32_16x16x32_bf16(aL[r], bL[c],
                                                            acc[r][c], 0, 0, 0);
      }
    p ^= 1;
  }
#undef ISSUE_STAGE
  // ---- epilogue: rel scaling, reference op order (unchanged)
  float rr[16], rc[4];
#pragma unroll
  for (int r = 0; r < 4; ++r)
#pragma unroll
    for (int e = 0; e < 4; ++e)
      rr[r * 4 + e] = rel[bi * 128 + wr * 64 + r * 16 + quad * 4 + e];
#pragma unroll
  for (int c = 0; c < 4; ++c) rc[c] = rel[bj * 128 + wc * 64 + c * 16 + lm];
#pragma unroll
  for (int r = 0; r < 4; ++r) {
    int grow = bi * 128 + wr * 64 + r * 16 + quad * 4;
#pragma unroll
    for (int c = 0; c < 4; ++c) {
      int gcol = bj * 128 + wc * 64 + c * 16 + lm;
#pragma unroll
      for (int e = 0; e < 4; ++e)
        ker[(size_t)(grow + e) * NTOK + gcol] =
            (acc[r][c][e] * rr[r * 4 + e]) * rc[c];
    }
  }
  if (bi != bj) {
    __syncthreads();
    float* Tw = (float*)(smem + wid * 4672);
#pragma unroll
    for (int c = 0; c < 4; ++c) {
#pragma unroll
      for (int r = 0; r < 4; ++r)
#pragma unroll
        for (int e = 0; e < 4; ++e)
          Tw[lm * 73 + r * 16 + quad * 4 + e] =
              (acc[r][c][e] * rc[c]) * rr[r * 4 + e];
      __syncthreads();
      int cc2 = lane >> 2, seg = lane & 3;
      float* dst = &ker[(size_t)(bj * 128 + wc * 64 + c * 16 + cc2) * NTOK +
                        bi * 128 + wr * 64 + seg * 16];
#pragma unroll
      for (int e = 0; e < 4; ++e)
        *(float4*)&dst[e * 4] = *(const float4*)&Tw[cc2 * 73 + seg * 16 + e * 4];
      __syncthreads();
    }
  }
}

// ---------------------------------------------------------------------------
// k_greedy v3 — r15 structure restored (cisT layout [token][t]: contiguous
// 512B winner-column gather, scatter eis store — measured 404us), plus ONE
// change: kj prefetch.  In wave0's post-reduce window (j known, acquire
// fence done), lanes 32-63 gather the winner's contiguous history column
// (2x 8B agent-atomic loads each, same 512B as r15's 64-lane version) while
// lanes 0-31 concurrently fetch this block's 128-float slice of ker[j] into
// LDS (512B, plain cached loads - ker is immutable during greedy).  Both
// gathers share one L3 round-trip; after B2 kj is an LDS read instead of a
// dependent ~0.4us global load on the serial chain.
// Same values, same summation order -> selection and absmax=0.0 unchanged.
// ---------------------------------------------------------------------------
__global__ __launch_bounds__(GT) void k_greedy(const float* __restrict__ ker,
                                               const float* __restrict__ feat,
                                               float* __restrict__ out,
                                               float* __restrict__ cisT,
                                               unsigned long long* __restrict__ slots) {
  __shared__ __align__(16) float histT[GT][132];   // [token][t], 67.6 KB
  __shared__ __align__(16) float colbuf[TOPK];
  __shared__ __align__(16) float kjbuf[GT];
  __shared__ unsigned long long redw[GT / 64];
  __shared__ unsigned long long bwS;
  __shared__ int selj[TOPK];
  int tid = threadIdx.x;
  int lane = tid & 63, wid = tid >> 6;
  int blk = blockIdx.x;
  int n = blk * GT + tid;
  float di2s = ker[(size_t)n * NTOK + n];
#pragma unroll
  for (int t = 0; t < TOPK; t += 4)
    *(float4*)&histT[tid][t] = (float4){0.f, 0.f, 0.f, 0.f};

  for (int i = 0; i < TOPK; ++i) {
    unsigned u = __float_as_uint(di2s);
    unsigned key = (u & 0x80000000u) ? ~u : (u | 0x80000000u);
    unsigned long long pk =
        ((unsigned long long)key << 32) | (unsigned)(NTOK - 1 - n);
    for (int o = 32; o >= 1; o >>= 1) {
      unsigned long long q = __shfl_down(pk, o, 64);
      if (q > pk) pk = q;
    }
    if (lane == 0) redw[wid] = pk;
    __syncthreads();   // B1: orders redw + drains iter-(i-1) cisT stores
    if (tid == 0) {
      unsigned long long m = redw[0];
      if (redw[1] > m) m = redw[1];
      __hip_atomic_store(&slots[((size_t)i * GB + blk) * 8], m,
                         __ATOMIC_RELEASE, __HIP_MEMORY_SCOPE_AGENT);
    }
    if (wid == 0) {
      unsigned long long v = 0;
      if (lane < GB) {
        do {
          v = __hip_atomic_load(&slots[((size_t)i * GB + lane) * 8],
                                __ATOMIC_RELAXED, __HIP_MEMORY_SCOPE_AGENT);
        } while (v == 0);
      }
      unsigned long long b1 = v;
      for (int o = 32; o >= 1; o >>= 1) {
        unsigned long long q = __shfl_down(b1, o, 64);
        if (q > b1) b1 = q;
      }
      b1 = __shfl(b1, 0, 64);
      __builtin_amdgcn_fence(__ATOMIC_ACQUIRE, "agent");
      int jw = NTOK - 1 - (int)(b1 & 0xffffffffu);
      if (lane < 32) {
        // this block's 128-float slice of row ker[jw] -> LDS (plain cached
        // loads: ker immutable during greedy, coherent at launch boundary)
        *(float4*)&kjbuf[lane * 4] =
            *(const float4*)(ker + (size_t)jw * NTOK + (size_t)blk * GT +
                             lane * 4);
      } else {
        // winner history column: contiguous cisT[jw][0..127], as 2x 8B
        // agent-relaxed atomic loads per lane (bypass stale L1/L2 lines),
        // acquire-fenced against the slot poll above.
        int le = lane - 32;
#pragma unroll
        for (int k = 0; k < 2; ++k) {
          int h = le + k * 32;   // u64 index 0..63 -> t = 2h, 2h+1
          unsigned long long cu = __hip_atomic_load(
              (const unsigned long long*)(cisT + (size_t)jw * TOPK) + h,
              __ATOMIC_RELAXED, __HIP_MEMORY_SCOPE_AGENT);
          union { unsigned long long u64; float f[2]; } cc; cc.u64 = cu;
          colbuf[h * 2]     = cc.f[0];
          colbuf[h * 2 + 1] = cc.f[1];
        }
      }
      if (lane == 0) bwS = b1;
    }
    __syncthreads();   // B2: colbuf + kjbuf + bwS published block-wide
    unsigned long long b1 = bwS;
    int j = NTOK - 1 - (int)(b1 & 0xffffffffu);
    unsigned kw = (unsigned)(b1 >> 32);
    unsigned du = (kw & 0x80000000u) ? (kw & 0x7fffffffu) : ~kw;
    float sd = sqrtf(__uint_as_float(du));
    if (tid == 0) selj[i] = j;
    float kj = kjbuf[tid];
    float proj = 0.f;
    for (int t = 0; t < i; t += 4) {
      float4 c4 = *(const float4*)&colbuf[t];
      float4 h4 = *(const float4*)&histT[tid][t];
      proj += c4.x * h4.x + c4.y * h4.y + c4.z * h4.z + c4.w * h4.w;
    }
    float eis = (kj - proj) / sd;
    __hip_atomic_store(&cisT[(size_t)n * TOPK + i], eis, __ATOMIC_RELAXED,
                       __HIP_MEMORY_SCOPE_AGENT);
    histT[tid][i] = eis;
    di2s -= eis * eis;
    if (n == j) di2s = NEGM;
  }
  __syncthreads();
  for (int k = blk; k < TOPK; k += GB) {
    int j = selj[k];
    const float4* src = (const float4*)(feat + (size_t)j * DIM);
    float4* dst = (float4*)(out + (size_t)k * DIM);
    dst[tid]       = src[tid];
    dst[tid + GT]  = src[tid + GT];
  }
}

// ---------------------------------------------------------------------------
// ws layout (bytes):
//   [0,262144)        slots: 128 iters x 32 blocks x 64B (zeroed each launch)
//   [262144,278528)   rel  : 4096 f32
//   [1MB, +8MB)       H    : 4096x1024 bf16
//   [1MB+8MB, +8MB)   L    : 4096x1024 bf16
//   [1MB+16MB, +2MB)  cisT : 4096x128 f32  (layout [token][t])
//   [1MB+20MB, +64MB) ker  : 4096x4096 f32
// total ~85 MB
// ---------------------------------------------------------------------------
extern "C" void kernel_launch(void* const* d_in, const int* in_sizes, int n_in,
                              void* d_out, int out_size, void* d_ws, size_t ws_size,
                              hipStream_t stream) {
  const float* feat = (const float*)d_in[0];
  const float* attn = (const float*)d_in[1];
  float* out = (float*)d_out;
  char* ws = (char*)d_ws;

  unsigned long long* slots = (unsigned long long*)ws;
  float* rel = (float*)(ws + 262144);
  __hip_bfloat16* H = (__hip_bfloat16*)(ws + (1 << 20));
  __hip_bfloat16* L = (__hip_bfloat16*)(ws + (1 << 20) + (8 << 20));
  float* cisT = (float*)(ws + (1 << 20) + (16 << 20));
  float* ker  = (float*)(ws + (1 << 20) + (16 << 20) + (4 << 20));

  hipMemsetAsync(d_ws, 0, 262144, stream);
  k_prep<<<1, 1024, 0, stream>>>(attn, rel);
  k_norm<<<NTOK, 256, 0, stream>>>(feat, H, L);
  k_gemm<<<dim3(32, 32), 256, 0, stream>>>(H, L, rel, ker);
  k_greedy<<<GB, GT, 0, stream>>>(ker, feat, out, cisT, slots);
}

// Round 4
// 626.235 us; speedup vs baseline: 1.1470x; 1.0159x over previous
//
#include <hip/hip_runtime.h>
#include <hip/hip_bf16.h>
#include <stdint.h>

#define NTOK 4096
#define DIM  1024
#define TOPK 128
#define GB   32      // greedy blocks (empirical optimum)
#define GT   128     // threads per greedy block; GB*GT == NTOK
#define NEGM -1e30f

typedef __attribute__((ext_vector_type(8))) short bf16x8;
typedef __attribute__((ext_vector_type(4))) float f32x4;

// ---------------------------------------------------------------------------
// k_prep: rel[n] = ((-a[n]) - min(-a) + 1e-6) / (max(-a) - min(-a))
// ---------------------------------------------------------------------------
__global__ __launch_bounds__(1024) void k_prep(const float* __restrict__ attn,
                                               float* __restrict__ rel) {
  __shared__ float smx[16], smn[16];
  int tid = threadIdx.x;
  float mx = -3.4e38f, mn = 3.4e38f;
  for (int n = tid; n < NTOK; n += 1024) {
    float a = attn[n];
    mx = fmaxf(mx, a); mn = fminf(mn, a);
  }
  for (int o = 32; o >= 1; o >>= 1) {
    mx = fmaxf(mx, __shfl_down(mx, o, 64));
    mn = fminf(mn, __shfl_down(mn, o, 64));
  }
  if ((tid & 63) == 0) { smx[tid >> 6] = mx; smn[tid >> 6] = mn; }
  __syncthreads();
  if (tid == 0) {
    float MX = smx[0], MN = smn[0];
    for (int w = 1; w < 16; ++w) { MX = fmaxf(MX, smx[w]); MN = fminf(MN, smn[w]); }
    smx[0] = MX; smn[0] = MN;
  }
  __syncthreads();
  float amax = smx[0], amin = smn[0];
  float rmin  = -amax;
  float range = (-amin) - rmin;
  for (int n = tid; n < NTOK; n += 1024) {
    float r = -attn[n];
    rel[n] = ((r - rmin) + 1e-6f) / range;
  }
}

// ---------------------------------------------------------------------------
// k_norm: xn = x/||x||, then EXACT bf16 split: hi=bf16(xn), lo=bf16(xn-hi).
// ---------------------------------------------------------------------------
__global__ __launch_bounds__(256) void k_norm(const float* __restrict__ x,
                                              __hip_bfloat16* __restrict__ H,
                                              __hip_bfloat16* __restrict__ L) {
  __shared__ float ps[4];
  int row = blockIdx.x, tid = threadIdx.x;
  const float4* xr = (const float4*)(x + (size_t)row * DIM);
  float4 v = xr[tid];
  float s = v.x * v.x + v.y * v.y + v.z * v.z + v.w * v.w;
  for (int o = 32; o >= 1; o >>= 1) s += __shfl_down(s, o, 64);
  if ((tid & 63) == 0) ps[tid >> 6] = s;
  __syncthreads();
  if (tid == 0) ps[0] = ps[0] + ps[1] + ps[2] + ps[3];
  __syncthreads();
  float nrm = sqrtf(ps[0]);
  float xf[4] = {v.x / nrm, v.y / nrm, v.z / nrm, v.w / nrm};
  __hip_bfloat16 hh[4], ll[4];
#pragma unroll
  for (int e = 0; e < 4; ++e) {
    hh[e] = __float2bfloat16(xf[e]);
    float lof = xf[e] - __bfloat162float(hh[e]);
    ll[e] = __float2bfloat16(lof);
  }
  *(short4*)(H + (size_t)row * DIM + tid * 4) = *(short4*)hh;
  *(short4*)(L + (size_t)row * DIM + tid * 4) = *(short4*)ll;
}

// ---------------------------------------------------------------------------
// k_gemm (MFMA split-bf16, FUSED-PHASE staging) — unchanged from r15.
// ---------------------------------------------------------------------------
__global__ __launch_bounds__(256) void k_gemm(const __hip_bfloat16* __restrict__ H,
                                              const __hip_bfloat16* __restrict__ L,
                                              const float* __restrict__ rel,
                                              float* __restrict__ ker) {
  int bi = blockIdx.y, bj = blockIdx.x;
  if (bi > bj) return;
  __shared__ __align__(16) char smem[65536];  // buf p at p*32768: AH,AL,BH,BL
  int tid = threadIdx.x;
  int lane = tid & 63, wid = tid >> 6;
  int wr = wid >> 1, wc = wid & 1;
  int lm = lane & 15, quad = lane >> 4;
  int lrow = lane >> 2;                       // 0..15 within a 16-row group
  int kcf  = (lane & 3) ^ ((lane >> 2) & 3);  // global chunk to fetch (swizzle)
  const __hip_bfloat16* M[4] = {
      H + (size_t)(bi * 128) * DIM, L + (size_t)(bi * 128) * DIM,   // A_H, A_L
      H + (size_t)(bj * 128) * DIM, L + (size_t)(bj * 128) * DIM};  // B_H, B_L
  f32x4 acc[4][4];
#pragma unroll
  for (int r = 0; r < 4; ++r)
#pragma unroll
    for (int c = 0; c < 4; ++c) acc[r][c] = (f32x4){0.f, 0.f, 0.f, 0.f};

#define ISSUE_STAGE(s, pbuf)                                                   \
  {                                                                            \
    int kk = (s) * 32;                                                         \
    char* base = smem + (pbuf) * 32768;                                        \
    _Pragma("unroll")                                                          \
    for (int m = 0; m < 4; ++m) {                                              \
      _Pragma("unroll")                                                        \
      for (int q = 0; q < 2; ++q) {                                            \
        int r0 = wid * 32 + q * 16;                                            \
        const __hip_bfloat16* g =                                              \
            M[m] + (size_t)(r0 + lrow) * DIM + kk + kcf * 8;                   \
        __builtin_amdgcn_global_load_lds(                                      \
            (const __attribute__((address_space(1))) void*)g,                  \
            (__attribute__((address_space(3))) void*)(base + m * 8192 +        \
                                                      r0 * 64),                \
            16, 0, 0);                                                         \
      }                                                                        \
    }                                                                          \
  }

  ISSUE_STAGE(0, 0);
  int p = 0;
  for (int s = 0; s < 32; ++s) {              // K = 32 stages x 32
    __syncthreads();   // stage-s loads landed (flew during prev compute)
    if (s + 1 < 32) ISSUE_STAGE(s + 1, 1 - p);
    const char* b = smem + p * 32768;
    bf16x8 aH[4], aL[4], bH[4], bL[4];
#pragma unroll
    for (int r = 0; r < 4; ++r) {
      int row = wr * 64 + r * 16 + lm;        // row&3 == lm&3
      int off = row * 64 + ((quad ^ (lm & 3)) * 16);
      aH[r] = *(const bf16x8*)(b + off);
      aL[r] = *(const bf16x8*)(b + 8192 + off);
    }
#pragma unroll
    for (int c = 0; c < 4; ++c) {
      int row = wc * 64 + c * 16 + lm;
      int off = row * 64 + ((quad ^ (lm & 3)) * 16);
      bH[c] = *(const bf16x8*)(b + 16384 + off);
      bL[c] = *(const bf16x8*)(b + 24576 + off);
    }
#pragma unroll
    for (int r = 0; r < 4; ++r)
#pragma unroll
      for (int c = 0; c < 4; ++c) {
        acc[r][c] = __builtin_amdgcn_mfma_f32_16x16x32_bf16(aH[r], bH[c],
                                                            acc[r][c], 0, 0, 0);
        acc[r][c] = __builtin_amdgcn_mfma_f32_16x16x32_bf16(aH[r], bL[c],
                                                            acc[r][c], 0, 0, 0);
        acc[r][c] = __builtin_amdgcn_mfma_f32_16x16x32_bf16(aL[r], bH[c],
                                                            acc[r][c], 0, 0, 0);
        acc[r][c] = __builtin_amdgcn_mfma_f32_16x16x32_bf16(aL[r], bL[c],
                                                            acc[r][c], 0, 0, 0);
      }
    p ^= 1;
  }
#undef ISSUE_STAGE
  // ---- epilogue: rel scaling, reference op order (unchanged)
  float rr[16], rc[4];
#pragma unroll
  for (int r = 0; r < 4; ++r)
#pragma unroll
    for (int e = 0; e < 4; ++e)
      rr[r * 4 + e] = rel[bi * 128 + wr * 64 + r * 16 + quad * 4 + e];
#pragma unroll
  for (int c = 0; c < 4; ++c) rc[c] = rel[bj * 128 + wc * 64 + c * 16 + lm];
#pragma unroll
  for (int r = 0; r < 4; ++r) {
    int grow = bi * 128 + wr * 64 + r * 16 + quad * 4;
#pragma unroll
    for (int c = 0; c < 4; ++c) {
      int gcol = bj * 128 + wc * 64 + c * 16 + lm;
#pragma unroll
      for (int e = 0; e < 4; ++e)
        ker[(size_t)(grow + e) * NTOK + gcol] =
            (acc[r][c][e] * rr[r * 4 + e]) * rc[c];
    }
  }
  if (bi != bj) {
    __syncthreads();
    float* Tw = (float*)(smem + wid * 4672);
#pragma unroll
    for (int c = 0; c < 4; ++c) {
#pragma unroll
      for (int r = 0; r < 4; ++r)
#pragma unroll
        for (int e = 0; e < 4; ++e)
          Tw[lm * 73 + r * 16 + quad * 4 + e] =
              (acc[r][c][e] * rc[c]) * rr[r * 4 + e];
      __syncthreads();
      int cc2 = lane >> 2, seg = lane & 3;
      float* dst = &ker[(size_t)(bj * 128 + wc * 64 + c * 16 + cc2) * NTOK +
                        bi * 128 + wr * 64 + seg * 16];
#pragma unroll
      for (int e = 0; e < 4; ++e)
        *(float4*)&dst[e * 4] = *(const float4*)&Tw[cc2 * 73 + seg * 16 + e * 4];
      __syncthreads();
    }
  }
}

// ---------------------------------------------------------------------------
// k_greedy v4b — r15 gather/kj structure untouched; TWO bit-exact chain trims
// (acquire fence KEPT this round as insurance; its removal is a separate
// future experiment):
//   (1) per-WAVE slots (64 = GB x 2): each wave's lane0 release-stores its
//       wave max right after the shuffle reduce — removes B1 + redw LDS hop
//       + tid0 combine from the pre-store chain.  Release correctness is
//       per-wave self-contained: the s_waitcnt vmcnt(0) implied by the
//       release drains the whole wave's cisT stores, and the poller waits
//       for ALL 64 slots, so every wave's iter-(i-1) history element is at
//       the coherence point before the column gather.
//   (2) histT transposed to [t][token]: proj's ds_read lane-stride was 132
//       dwords = 4 banks -> 8-way conflict (measured 49152 conflict-cycles
//       = 384cy/iter).  Transposed: lane stride 4B = 2-way = free; eis
//       store also conflict-free.
// Same values, same summation order -> selection and absmax=0.0 unchanged.
// ---------------------------------------------------------------------------
__global__ __launch_bounds__(GT) void k_greedy(const float* __restrict__ ker,
                                               const float* __restrict__ feat,
                                               float* __restrict__ out,
                                               float* __restrict__ cisT,
                                               unsigned long long* __restrict__ slots) {
  __shared__ __align__(16) float histT[TOPK][GT];  // [t][token], 64 KB
  __shared__ __align__(16) float colbuf[TOPK];
  __shared__ unsigned long long bwS;
  __shared__ int selj[TOPK];
  int tid = threadIdx.x;
  int lane = tid & 63, wid = tid >> 6;
  int blk = blockIdx.x;
  int n = blk * GT + tid;
  float di2s = ker[(size_t)n * NTOK + n];
  for (int t = 0; t < TOPK; ++t) histT[t][tid] = 0.f;

  for (int i = 0; i < TOPK; ++i) {
    unsigned u = __float_as_uint(di2s);
    unsigned key = (u & 0x80000000u) ? ~u : (u | 0x80000000u);
    unsigned long long pk =
        ((unsigned long long)key << 32) | (unsigned)(NTOK - 1 - n);
    for (int o = 32; o >= 1; o >>= 1) {
      unsigned long long q = __shfl_down(pk, o, 64);
      if (q > pk) pk = q;
    }
    // per-wave slot: release store straight after the in-wave reduce.
    if (lane == 0)
      __hip_atomic_store(&slots[((size_t)i * (GB * 2) + blk * 2 + wid) * 8], pk,
                         __ATOMIC_RELEASE, __HIP_MEMORY_SCOPE_AGENT);
    if (wid == 0) {
      unsigned long long v;
      do {
        v = __hip_atomic_load(&slots[((size_t)i * (GB * 2) + lane) * 8],
                              __ATOMIC_RELAXED, __HIP_MEMORY_SCOPE_AGENT);
      } while (v == 0);
      unsigned long long b1 = v;
      for (int o = 32; o >= 1; o >>= 1) {
        unsigned long long q = __shfl_down(b1, o, 64);
        if (q > b1) b1 = q;
      }
      b1 = __shfl(b1, 0, 64);
      __builtin_amdgcn_fence(__ATOMIC_ACQUIRE, "agent");
      int jw = NTOK - 1 - (int)(b1 & 0xffffffffu);
      // winner history column: contiguous cisT[jw][0..127], 64 lanes x 8B
      // agent-relaxed atomic loads (coherence point; release-ordered behind
      // the slot values observed above).
      unsigned long long cu = __hip_atomic_load(
          (const unsigned long long*)(cisT + (size_t)jw * TOPK) + lane,
          __ATOMIC_RELAXED, __HIP_MEMORY_SCOPE_AGENT);
      union { unsigned long long u64; float f[2]; } cc; cc.u64 = cu;
      colbuf[lane * 2]     = cc.f[0];
      colbuf[lane * 2 + 1] = cc.f[1];
      if (lane == 0) bwS = b1;
    }
    __syncthreads();   // B2: colbuf + bwS published block-wide
    unsigned long long b1 = bwS;
    int j = NTOK - 1 - (int)(b1 & 0xffffffffu);
    unsigned kw = (unsigned)(b1 >> 32);
    unsigned du = (kw & 0x80000000u) ? (kw & 0x7fffffffu) : ~kw;
    float sd = sqrtf(__uint_as_float(du));
    if (tid == 0) selj[i] = j;
    float kj = ker[(size_t)j * NTOK + n];   // issued here, consumed after proj
    float proj = 0.f;
    for (int t = 0; t < i; t += 4) {
      float4 c4 = *(const float4*)&colbuf[t];
      proj += c4.x * histT[t][tid] + c4.y * histT[t + 1][tid] +
              c4.z * histT[t + 2][tid] + c4.w * histT[t + 3][tid];
    }
    float eis = (kj - proj) / sd;
    __hip_atomic_store(&cisT[(size_t)n * TOPK + i], eis, __ATOMIC_RELAXED,
                       __HIP_MEMORY_SCOPE_AGENT);
    histT[i][tid] = eis;
    di2s -= eis * eis;
    if (n == j) di2s = NEGM;
  }
  __syncthreads();
  for (int k = blk; k < TOPK; k += GB) {
    int j = selj[k];
    const float4* src = (const float4*)(feat + (size_t)j * DIM);
    float4* dst = (float4*)(out + (size_t)k * DIM);
    dst[tid]       = src[tid];
    dst[tid + GT]  = src[tid + GT];
  }
}

// ---------------------------------------------------------------------------
// ws layout (bytes):
//   [0,524288)        slots: 128 iters x 64 wave-slots x 64B (zeroed/launch)
//   [524288,540672)   rel  : 4096 f32
//   [1MB, +8MB)       H    : 4096x1024 bf16
//   [1MB+8MB, +8MB)   L    : 4096x1024 bf16
//   [1MB+16MB, +2MB)  cisT : 4096x128 f32  (layout [token][t])
//   [1MB+20MB, +64MB) ker  : 4096x4096 f32
// total ~85 MB
// ---------------------------------------------------------------------------
extern "C" void kernel_launch(void* const* d_in, const int* in_sizes, int n_in,
                              void* d_out, int out_size, void* d_ws, size_t ws_size,
                              hipStream_t stream) {
  const float* feat = (const float*)d_in[0];
  const float* attn = (const float*)d_in[1];
  float* out = (float*)d_out;
  char* ws = (char*)d_ws;

  unsigned long long* slots = (unsigned long long*)ws;
  float* rel = (float*)(ws + 524288);
  __hip_bfloat16* H = (__hip_bfloat16*)(ws + (1 << 20));
  __hip_bfloat16* L = (__hip_bfloat16*)(ws + (1 << 20) + (8 << 20));
  float* cisT = (float*)(ws + (1 << 20) + (16 << 20));
  float* ker  = (float*)(ws + (1 << 20) + (16 << 20) + (4 << 20));

  hipMemsetAsync(d_ws, 0, 524288, stream);
  k_prep<<<1, 1024, 0, stream>>>(attn, rel);
  k_norm<<<NTOK, 256, 0, stream>>>(feat, H, L);
  k_gemm<<<dim3(32, 32), 256, 0, stream>>>(H, L, rel, ker);
  k_greedy<<<GB, GT, 0, stream>>>(ker, feat, out, cisT, slots);
}

// Round 5
// 595.972 us; speedup vs baseline: 1.2052x; 1.0508x over previous
//
#include <hip/hip_runtime.h>
#include <hip/hip_bf16.h>
#include <stdint.h>

#define NTOK 4096
#define DIM  1024
#define TOPK 128
#define GB   32      // greedy blocks (empirical optimum; do not change — r4 lesson)
#define GT   128     // threads per greedy block; GB*GT == NTOK
#define NEGM -1e30f

typedef __attribute__((ext_vector_type(8))) short bf16x8;
typedef __attribute__((ext_vector_type(4))) float f32x4;

// ---------------------------------------------------------------------------
// k_norm: xn = x/||x||, then EXACT bf16 split: hi=bf16(xn), lo=bf16(xn-hi).
// ---------------------------------------------------------------------------
__global__ __launch_bounds__(256) void k_norm(const float* __restrict__ x,
                                              __hip_bfloat16* __restrict__ H,
                                              __hip_bfloat16* __restrict__ L) {
  __shared__ float ps[4];
  int row = blockIdx.x, tid = threadIdx.x;
  const float4* xr = (const float4*)(x + (size_t)row * DIM);
  float4 v = xr[tid];
  float s = v.x * v.x + v.y * v.y + v.z * v.z + v.w * v.w;
  for (int o = 32; o >= 1; o >>= 1) s += __shfl_down(s, o, 64);
  if ((tid & 63) == 0) ps[tid >> 6] = s;
  __syncthreads();
  if (tid == 0) ps[0] = ps[0] + ps[1] + ps[2] + ps[3];
  __syncthreads();
  float nrm = sqrtf(ps[0]);
  float xf[4] = {v.x / nrm, v.y / nrm, v.z / nrm, v.w / nrm};
  __hip_bfloat16 hh[4], ll[4];
#pragma unroll
  for (int e = 0; e < 4; ++e) {
    hh[e] = __float2bfloat16(xf[e]);
    float lof = xf[e] - __bfloat162float(hh[e]);
    ll[e] = __float2bfloat16(lof);
  }
  *(short4*)(H + (size_t)row * DIM + tid * 4) = *(short4*)hh;
  *(short4*)(L + (size_t)row * DIM + tid * 4) = *(short4*)ll;
}

// ---------------------------------------------------------------------------
// k_gemm (MFMA split-bf16, FUSED-PHASE staging) — r15 structure, with k_prep
// FUSED IN: each block computes amax/amin over attn itself (fmin/fmax are
// order-insensitive -> bit-identical rmin/range vs the old 1024-thread
// k_prep) and evaluates its 20 rel values inline in the epilogue with the
// identical expression ((-a - rmin) + 1e-6f)/range.  Removes one kernel
// launch + gap from the serial pipeline.  K-loop untouched.
// ---------------------------------------------------------------------------
__global__ __launch_bounds__(256) void k_gemm(const __hip_bfloat16* __restrict__ H,
                                              const __hip_bfloat16* __restrict__ L,
                                              const float* __restrict__ attn,
                                              float* __restrict__ ker) {
  int bi = blockIdx.y, bj = blockIdx.x;
  if (bi > bj) return;
  __shared__ __align__(16) char smem[65536];  // buf p at p*32768: AH,AL,BH,BL
  __shared__ float smm[8];                    // 4 waves x {max, min}
  int tid = threadIdx.x;
  int lane = tid & 63, wid = tid >> 6;
  int wr = wid >> 1, wc = wid & 1;
  int lm = lane & 15, quad = lane >> 4;
  int lrow = lane >> 2;                       // 0..15 within a 16-row group
  int kcf  = (lane & 3) ^ ((lane >> 2) & 3);  // global chunk to fetch (swizzle)
  const __hip_bfloat16* M[4] = {
      H + (size_t)(bi * 128) * DIM, L + (size_t)(bi * 128) * DIM,   // A_H, A_L
      H + (size_t)(bj * 128) * DIM, L + (size_t)(bj * 128) * DIM};  // B_H, B_L
  f32x4 acc[4][4];
#pragma unroll
  for (int r = 0; r < 4; ++r)
#pragma unroll
    for (int c = 0; c < 4; ++c) acc[r][c] = (f32x4){0.f, 0.f, 0.f, 0.f};

#define ISSUE_STAGE(s, pbuf)                                                   \
  {                                                                            \
    int kk = (s) * 32;                                                         \
    char* base = smem + (pbuf) * 32768;                                        \
    _Pragma("unroll")                                                          \
    for (int m = 0; m < 4; ++m) {                                              \
      _Pragma("unroll")                                                        \
      for (int q = 0; q < 2; ++q) {                                            \
        int r0 = wid * 32 + q * 16;                                            \
        const __hip_bfloat16* g =                                              \
            M[m] + (size_t)(r0 + lrow) * DIM + kk + kcf * 8;                   \
        __builtin_amdgcn_global_load_lds(                                      \
            (const __attribute__((address_space(1))) void*)g,                  \
            (__attribute__((address_space(3))) void*)(base + m * 8192 +        \
                                                      r0 * 64),                \
            16, 0, 0);                                                         \
      }                                                                        \
    }                                                                          \
  }

  ISSUE_STAGE(0, 0);

  // ---- fused rel-prep: block-local min/max over attn (order-insensitive)
  float amx = -3.4e38f, amn = 3.4e38f;
  for (int t2 = tid; t2 < NTOK; t2 += 256) {
    float a = attn[t2];
    amx = fmaxf(amx, a); amn = fminf(amn, a);
  }
  for (int o = 32; o >= 1; o >>= 1) {
    amx = fmaxf(amx, __shfl_down(amx, o, 64));
    amn = fminf(amn, __shfl_down(amn, o, 64));
  }
  if (lane == 0) { smm[wid] = amx; smm[4 + wid] = amn; }
  __syncthreads();
  float amax = fmaxf(fmaxf(smm[0], smm[1]), fmaxf(smm[2], smm[3]));
  float amin = fminf(fminf(smm[4], smm[5]), fminf(smm[6], smm[7]));
  float rmin  = -amax;
  float range = (-amin) - rmin;

  int p = 0;
  for (int s = 0; s < 32; ++s) {              // K = 32 stages x 32
    __syncthreads();   // stage-s loads landed (flew during prev compute)
    if (s + 1 < 32) ISSUE_STAGE(s + 1, 1 - p);
    const char* b = smem + p * 32768;
    bf16x8 aH[4], aL[4], bH[4], bL[4];
#pragma unroll
    for (int r = 0; r < 4; ++r) {
      int row = wr * 64 + r * 16 + lm;        // row&3 == lm&3
      int off = row * 64 + ((quad ^ (lm & 3)) * 16);
      aH[r] = *(const bf16x8*)(b + off);
      aL[r] = *(const bf16x8*)(b + 8192 + off);
    }
#pragma unroll
    for (int c = 0; c < 4; ++c) {
      int row = wc * 64 + c * 16 + lm;
      int off = row * 64 + ((quad ^ (lm & 3)) * 16);
      bH[c] = *(const bf16x8*)(b + 16384 + off);
      bL[c] = *(const bf16x8*)(b + 24576 + off);
    }
#pragma unroll
    for (int r = 0; r < 4; ++r)
#pragma unroll
      for (int c = 0; c < 4; ++c) {
        acc[r][c] = __builtin_amdgcn_mfma_f32_16x16x32_bf16(aH[r], bH[c],
                                                            acc[r][c], 0, 0, 0);
        acc[r][c] = __builtin_amdgcn_mfma_f32_16x16x32_bf16(aH[r], bL[c],
                                                            acc[r][c], 0, 0, 0);
        acc[r][c] = __builtin_amdgcn_mfma_f32_16x16x32_bf16(aL[r], bH[c],
                                                            acc[r][c], 0, 0, 0);
        acc[r][c] = __builtin_amdgcn_mfma_f32_16x16x32_bf16(aL[r], bL[c],
                                                            acc[r][c], 0, 0, 0);
      }
    p ^= 1;
  }
#undef ISSUE_STAGE
  // ---- epilogue: rel scaling (inline, bit-identical expression)
#define RELV(idx) ((((-attn[(idx)]) - rmin) + 1e-6f) / range)
  float rr[16], rc[4];
#pragma unroll
  for (int r = 0; r < 4; ++r)
#pragma unroll
    for (int e = 0; e < 4; ++e)
      rr[r * 4 + e] = RELV(bi * 128 + wr * 64 + r * 16 + quad * 4 + e);
#pragma unroll
  for (int c = 0; c < 4; ++c) rc[c] = RELV(bj * 128 + wc * 64 + c * 16 + lm);
#undef RELV
#pragma unroll
  for (int r = 0; r < 4; ++r) {
    int grow = bi * 128 + wr * 64 + r * 16 + quad * 4;
#pragma unroll
    for (int c = 0; c < 4; ++c) {
      int gcol = bj * 128 + wc * 64 + c * 16 + lm;
#pragma unroll
      for (int e = 0; e < 4; ++e)
        ker[(size_t)(grow + e) * NTOK + gcol] =
            (acc[r][c][e] * rr[r * 4 + e]) * rc[c];
    }
  }
  if (bi != bj) {
    __syncthreads();
    float* Tw = (float*)(smem + wid * 4672);
#pragma unroll
    for (int c = 0; c < 4; ++c) {
#pragma unroll
      for (int r = 0; r < 4; ++r)
#pragma unroll
        for (int e = 0; e < 4; ++e)
          Tw[lm * 73 + r * 16 + quad * 4 + e] =
              (acc[r][c][e] * rc[c]) * rr[r * 4 + e];
      __syncthreads();
      int cc2 = lane >> 2, seg = lane & 3;
      float* dst = &ker[(size_t)(bj * 128 + wc * 64 + c * 16 + cc2) * NTOK +
                        bi * 128 + wr * 64 + seg * 16];
#pragma unroll
      for (int e = 0; e < 4; ++e)
        *(float4*)&dst[e * 4] = *(const float4*)&Tw[cc2 * 73 + seg * 16 + e * 4];
      __syncthreads();
    }
  }
}

// ---------------------------------------------------------------------------
// k_greedy v5 — EXACT r15 handshake (per-block slots, B1+redw+tid0 combine,
// acquire fence, 64-lane contiguous colbuf gather, [token][t] cisT layout,
// histT[GT][132]) with ONE restructure: the two post-reduce round-trips
// (colbuf gather, kj row load) now OVERLAP instead of serializing.
//   r15: gather(~0.35us, in wave0) -> B2 -> kj issue -> proj(~0.05) ->
//        kj tail exposed (~0.25us on the chain).
//   v5:  publish bwS + B2 right after the reduce; then ALL threads issue
//        kj while wave0 concurrently gathers the winner column; B3 syncs
//        colbuf.  kj has gather+B3+proj to land -> fully hidden.
// No divergent-branch fetch serialization (v3's bug), no slot-count change
// (v4b's bug).  Same values, same order -> selection, absmax=0.0 unchanged.
// ---------------------------------------------------------------------------
__global__ __launch_bounds__(GT) void k_greedy(const float* __restrict__ ker,
                                               const float* __restrict__ feat,
                                               float* __restrict__ out,
                                               float* __restrict__ cisT,
                                               unsigned long long* __restrict__ slots) {
  __shared__ __align__(16) float histT[GT][132];   // [token][t], 67.6 KB
  __shared__ __align__(16) float colbuf[TOPK];
  __shared__ unsigned long long redw[GT / 64];
  __shared__ unsigned long long bwS;
  __shared__ int selj[TOPK];
  int tid = threadIdx.x;
  int lane = tid & 63, wid = tid >> 6;
  int blk = blockIdx.x;
  int n = blk * GT + tid;
  float di2s = ker[(size_t)n * NTOK + n];
#pragma unroll
  for (int t = 0; t < TOPK; t += 4)
    *(float4*)&histT[tid][t] = (float4){0.f, 0.f, 0.f, 0.f};

  for (int i = 0; i < TOPK; ++i) {
    unsigned u = __float_as_uint(di2s);
    unsigned key = (u & 0x80000000u) ? ~u : (u | 0x80000000u);
    unsigned long long pk =
        ((unsigned long long)key << 32) | (unsigned)(NTOK - 1 - n);
    for (int o = 32; o >= 1; o >>= 1) {
      unsigned long long q = __shfl_down(pk, o, 64);
      if (q > pk) pk = q;
    }
    if (lane == 0) redw[wid] = pk;
    __syncthreads();   // B1: orders redw + drains iter-(i-1) cisT stores
    if (tid == 0) {
      unsigned long long m = redw[0];
      if (redw[1] > m) m = redw[1];
      __hip_atomic_store(&slots[((size_t)i * GB + blk) * 8], m,
                         __ATOMIC_RELEASE, __HIP_MEMORY_SCOPE_AGENT);
    }
    if (wid == 0) {
      unsigned long long v = 0;
      if (lane < GB) {
        do {
          v = __hip_atomic_load(&slots[((size_t)i * GB + lane) * 8],
                                __ATOMIC_RELAXED, __HIP_MEMORY_SCOPE_AGENT);
        } while (v == 0);
      }
      unsigned long long b1 = v;
      for (int o = 32; o >= 1; o >>= 1) {
        unsigned long long q = __shfl_down(b1, o, 64);
        if (q > b1) b1 = q;
      }
      b1 = __shfl(b1, 0, 64);
      __builtin_amdgcn_fence(__ATOMIC_ACQUIRE, "agent");
      if (lane == 0) bwS = b1;
    }
    __syncthreads();   // B2 (early): bwS published; gather moved below
    unsigned long long b1 = bwS;
    int j = NTOK - 1 - (int)(b1 & 0xffffffffu);
    unsigned kw = (unsigned)(b1 >> 32);
    unsigned du = (kw & 0x80000000u) ? (kw & 0x7fffffffu) : ~kw;
    float sd = sqrtf(__uint_as_float(du));
    if (tid == 0) selj[i] = j;
    float kj = ker[(size_t)j * NTOK + n];  // issued NOW by all threads;
                                           // lands under the gather below
    if (wid == 0) {
      // winner history column: contiguous cisT[j][0..127], 64 lanes x 8B
      // agent-relaxed atomic loads (coherence point), ordered behind the
      // acquire fence executed by this same wave above.
      unsigned long long cu = __hip_atomic_load(
          (const unsigned long long*)(cisT + (size_t)j * TOPK) + lane,
          __ATOMIC_RELAXED, __HIP_MEMORY_SCOPE_AGENT);
      union { unsigned long long u64; float f[2]; } cc; cc.u64 = cu;
      colbuf[lane * 2]     = cc.f[0];
      colbuf[lane * 2 + 1] = cc.f[1];
    }
    __syncthreads();   // B3: colbuf ready; kj landed in parallel
    float proj = 0.f;
    for (int t = 0; t < i; t += 4) {
      float4 c4 = *(const float4*)&colbuf[t];
      float4 h4 = *(const float4*)&histT[tid][t];
      proj += c4.x * h4.x + c4.y * h4.y + c4.z * h4.z + c4.w * h4.w;
    }
    float eis = (kj - proj) / sd;
    __hip_atomic_store(&cisT[(size_t)n * TOPK + i], eis, __ATOMIC_RELAXED,
                       __HIP_MEMORY_SCOPE_AGENT);
    histT[tid][i] = eis;
    di2s -= eis * eis;
    if (n == j) di2s = NEGM;
  }
  __syncthreads();
  for (int k = blk; k < TOPK; k += GB) {
    int j = selj[k];
    const float4* src = (const float4*)(feat + (size_t)j * DIM);
    float4* dst = (float4*)(out + (size_t)k * DIM);
    dst[tid]       = src[tid];
    dst[tid + GT]  = src[tid + GT];
  }
}

// ---------------------------------------------------------------------------
// ws layout (bytes):
//   [0,262144)        slots: 128 iters x 32 blocks x 64B (zeroed each launch)
//   [1MB, +8MB)       H    : 4096x1024 bf16
//   [1MB+8MB, +8MB)   L    : 4096x1024 bf16
//   [1MB+16MB, +2MB)  cisT : 4096x128 f32  (layout [token][t])
//   [1MB+20MB, +64MB) ker  : 4096x4096 f32
// total ~85 MB   (rel buffer gone — fused into k_gemm)
// ---------------------------------------------------------------------------
extern "C" void kernel_launch(void* const* d_in, const int* in_sizes, int n_in,
                              void* d_out, int out_size, void* d_ws, size_t ws_size,
                              hipStream_t stream) {
  const float* feat = (const float*)d_in[0];
  const float* attn = (const float*)d_in[1];
  float* out = (float*)d_out;
  char* ws = (char*)d_ws;

  unsigned long long* slots = (unsigned long long*)ws;
  __hip_bfloat16* H = (__hip_bfloat16*)(ws + (1 << 20));
  __hip_bfloat16* L = (__hip_bfloat16*)(ws + (1 << 20) + (8 << 20));
  float* cisT = (float*)(ws + (1 << 20) + (16 << 20));
  float* ker  = (float*)(ws + (1 << 20) + (16 << 20) + (4 << 20));

  hipMemsetAsync(d_ws, 0, 262144, stream);
  k_norm<<<NTOK, 256, 0, stream>>>(feat, H, L);
  k_gemm<<<dim3(32, 32), 256, 0, stream>>>(H, L, attn, ker);
  k_greedy<<<GB, GT, 0, stream>>>(ker, feat, out, cisT, slots);
}

// Round 6
// 573.779 us; speedup vs baseline: 1.2518x; 1.0387x over previous
//
#include <hip/hip_runtime.h>
#include <hip/hip_bf16.h>
#include <stdint.h>

#define NTOK 4096
#define DIM  1024
#define TOPK 128
#define GB   32      // greedy blocks (empirical optimum; r4 lesson: don't change)
#define GT   128     // threads per greedy block; GB*GT == NTOK
#define NEGM -1e30f

typedef __attribute__((ext_vector_type(8))) short bf16x8;
typedef __attribute__((ext_vector_type(4))) float f32x4;

// ---------------------------------------------------------------------------
// k_prep: rel[n] = ((-a[n]) - min(-a) + 1e-6) / (max(-a) - min(-a))
// ---------------------------------------------------------------------------
__global__ __launch_bounds__(1024) void k_prep(const float* __restrict__ attn,
                                               float* __restrict__ rel) {
  __shared__ float smx[16], smn[16];
  int tid = threadIdx.x;
  float mx = -3.4e38f, mn = 3.4e38f;
  for (int n = tid; n < NTOK; n += 1024) {
    float a = attn[n];
    mx = fmaxf(mx, a); mn = fminf(mn, a);
  }
  for (int o = 32; o >= 1; o >>= 1) {
    mx = fmaxf(mx, __shfl_down(mx, o, 64));
    mn = fminf(mn, __shfl_down(mn, o, 64));
  }
  if ((tid & 63) == 0) { smx[tid >> 6] = mx; smn[tid >> 6] = mn; }
  __syncthreads();
  if (tid == 0) {
    float MX = smx[0], MN = smn[0];
    for (int w = 1; w < 16; ++w) { MX = fmaxf(MX, smx[w]); MN = fminf(MN, smn[w]); }
    smx[0] = MX; smn[0] = MN;
  }
  __syncthreads();
  float amax = smx[0], amin = smn[0];
  float rmin  = -amax;
  float range = (-amin) - rmin;
  for (int n = tid; n < NTOK; n += 1024) {
    float r = -attn[n];
    rel[n] = ((r - rmin) + 1e-6f) / range;
  }
}

// ---------------------------------------------------------------------------
// k_norm: xn = x/||x||, then EXACT bf16 split: hi=bf16(xn), lo=bf16(xn-hi).
// ---------------------------------------------------------------------------
__global__ __launch_bounds__(256) void k_norm(const float* __restrict__ x,
                                              __hip_bfloat16* __restrict__ H,
                                              __hip_bfloat16* __restrict__ L) {
  __shared__ float ps[4];
  int row = blockIdx.x, tid = threadIdx.x;
  const float4* xr = (const float4*)(x + (size_t)row * DIM);
  float4 v = xr[tid];
  float s = v.x * v.x + v.y * v.y + v.z * v.z + v.w * v.w;
  for (int o = 32; o >= 1; o >>= 1) s += __shfl_down(s, o, 64);
  if ((tid & 63) == 0) ps[tid >> 6] = s;
  __syncthreads();
  if (tid == 0) ps[0] = ps[0] + ps[1] + ps[2] + ps[3];
  __syncthreads();
  float nrm = sqrtf(ps[0]);
  float xf[4] = {v.x / nrm, v.y / nrm, v.z / nrm, v.w / nrm};
  __hip_bfloat16 hh[4], ll[4];
#pragma unroll
  for (int e = 0; e < 4; ++e) {
    hh[e] = __float2bfloat16(xf[e]);
    float lof = xf[e] - __bfloat162float(hh[e]);
    ll[e] = __float2bfloat16(lof);
  }
  *(short4*)(H + (size_t)row * DIM + tid * 4) = *(short4*)hh;
  *(short4*)(L + (size_t)row * DIM + tid * 4) = *(short4*)ll;
}

// ---------------------------------------------------------------------------
// k_gemm (MFMA split-bf16, FUSED-PHASE staging) — r15, untouched.
// ---------------------------------------------------------------------------
__global__ __launch_bounds__(256) void k_gemm(const __hip_bfloat16* __restrict__ H,
                                              const __hip_bfloat16* __restrict__ L,
                                              const float* __restrict__ rel,
                                              float* __restrict__ ker) {
  int bi = blockIdx.y, bj = blockIdx.x;
  if (bi > bj) return;
  __shared__ __align__(16) char smem[65536];  // buf p at p*32768: AH,AL,BH,BL
  int tid = threadIdx.x;
  int lane = tid & 63, wid = tid >> 6;
  int wr = wid >> 1, wc = wid & 1;
  int lm = lane & 15, quad = lane >> 4;
  int lrow = lane >> 2;                       // 0..15 within a 16-row group
  int kcf  = (lane & 3) ^ ((lane >> 2) & 3);  // global chunk to fetch (swizzle)
  const __hip_bfloat16* M[4] = {
      H + (size_t)(bi * 128) * DIM, L + (size_t)(bi * 128) * DIM,   // A_H, A_L
      H + (size_t)(bj * 128) * DIM, L + (size_t)(bj * 128) * DIM};  // B_H, B_L
  f32x4 acc[4][4];
#pragma unroll
  for (int r = 0; r < 4; ++r)
#pragma unroll
    for (int c = 0; c < 4; ++c) acc[r][c] = (f32x4){0.f, 0.f, 0.f, 0.f};

#define ISSUE_STAGE(s, pbuf)                                                   \
  {                                                                            \
    int kk = (s) * 32;                                                         \
    char* base = smem + (pbuf) * 32768;                                        \
    _Pragma("unroll")                                                          \
    for (int m = 0; m < 4; ++m) {                                              \
      _Pragma("unroll")                                                        \
      for (int q = 0; q < 2; ++q) {                                            \
        int r0 = wid * 32 + q * 16;                                            \
        const __hip_bfloat16* g =                                              \
            M[m] + (size_t)(r0 + lrow) * DIM + kk + kcf * 8;                   \
        __builtin_amdgcn_global_load_lds(                                      \
            (const __attribute__((address_space(1))) void*)g,                  \
            (__attribute__((address_space(3))) void*)(base + m * 8192 +        \
                                                      r0 * 64),                \
            16, 0, 0);                                                         \
      }                                                                        \
    }                                                                          \
  }

  ISSUE_STAGE(0, 0);
  int p = 0;
  for (int s = 0; s < 32; ++s) {              // K = 32 stages x 32
    __syncthreads();   // stage-s loads landed (flew during prev compute)
    if (s + 1 < 32) ISSUE_STAGE(s + 1, 1 - p);
    const char* b = smem + p * 32768;
    bf16x8 aH[4], aL[4], bH[4], bL[4];
#pragma unroll
    for (int r = 0; r < 4; ++r) {
      int row = wr * 64 + r * 16 + lm;        // row&3 == lm&3
      int off = row * 64 + ((quad ^ (lm & 3)) * 16);
      aH[r] = *(const bf16x8*)(b + off);
      aL[r] = *(const bf16x8*)(b + 8192 + off);
    }
#pragma unroll
    for (int c = 0; c < 4; ++c) {
      int row = wc * 64 + c * 16 + lm;
      int off = row * 64 + ((quad ^ (lm & 3)) * 16);
      bH[c] = *(const bf16x8*)(b + 16384 + off);
      bL[c] = *(const bf16x8*)(b + 24576 + off);
    }
#pragma unroll
    for (int r = 0; r < 4; ++r)
#pragma unroll
      for (int c = 0; c < 4; ++c) {
        acc[r][c] = __builtin_amdgcn_mfma_f32_16x16x32_bf16(aH[r], bH[c],
                                                            acc[r][c], 0, 0, 0);
        acc[r][c] = __builtin_amdgcn_mfma_f32_16x16x32_bf16(aH[r], bL[c],
                                                            acc[r][c], 0, 0, 0);
        acc[r][c] = __builtin_amdgcn_mfma_f32_16x16x32_bf16(aL[r], bH[c],
                                                            acc[r][c], 0, 0, 0);
        acc[r][c] = __builtin_amdgcn_mfma_f32_16x16x32_bf16(aL[r], bL[c],
                                                            acc[r][c], 0, 0, 0);
      }
    p ^= 1;
  }
#undef ISSUE_STAGE
  // ---- epilogue: rel scaling, reference op order (unchanged)
  float rr[16], rc[4];
#pragma unroll
  for (int r = 0; r < 4; ++r)
#pragma unroll
    for (int e = 0; e < 4; ++e)
      rr[r * 4 + e] = rel[bi * 128 + wr * 64 + r * 16 + quad * 4 + e];
#pragma unroll
  for (int c = 0; c < 4; ++c) rc[c] = rel[bj * 128 + wc * 64 + c * 16 + lm];
#pragma unroll
  for (int r = 0; r < 4; ++r) {
    int grow = bi * 128 + wr * 64 + r * 16 + quad * 4;
#pragma unroll
    for (int c = 0; c < 4; ++c) {
      int gcol = bj * 128 + wc * 64 + c * 16 + lm;
#pragma unroll
      for (int e = 0; e < 4; ++e)
        ker[(size_t)(grow + e) * NTOK + gcol] =
            (acc[r][c][e] * rr[r * 4 + e]) * rc[c];
    }
  }
  if (bi != bj) {
    __syncthreads();
    float* Tw = (float*)(smem + wid * 4672);
#pragma unroll
    for (int c = 0; c < 4; ++c) {
#pragma unroll
      for (int r = 0; r < 4; ++r)
#pragma unroll
        for (int e = 0; e < 4; ++e)
          Tw[lm * 73 + r * 16 + quad * 4 + e] =
              (acc[r][c][e] * rc[c]) * rr[r * 4 + e];
      __syncthreads();
      int cc2 = lane >> 2, seg = lane & 3;
      float* dst = &ker[(size_t)(bj * 128 + wc * 64 + c * 16 + cc2) * NTOK +
                        bi * 128 + wr * 64 + seg * 16];
#pragma unroll
      for (int e = 0; e < 4; ++e)
        *(float4*)&dst[e * 4] = *(const float4*)&Tw[cc2 * 73 + seg * 16 + e * 4];
      __syncthreads();
    }
  }
}

// ---------------------------------------------------------------------------
// k_greedy v6 — EXACT r15 structure (measured 404us) with ONE micro-trim:
// the per-iteration acquire fence is removed.  Safety: every cross-block
// datum read after the poll is either (a) an agent-scope relaxed ATOMIC
// load (slot poll, colbuf gather) that reads the coherence point directly,
// with its address DATA-DEPENDENT on the polled slot value (cannot be
// hoisted above the poll), or (b) immutable during this kernel (ker, feat).
// Producer side: __syncthreads (B1) drains each wave's eis stores (vmcnt(0))
// before tid0's release slot-store.  The fence only added an L1/L2
// invalidate (~150cy) to the serial chain each iteration.
// Same values, same summation order -> selection and absmax=0.0 unchanged.
// ---------------------------------------------------------------------------
__global__ __launch_bounds__(GT) void k_greedy(const float* __restrict__ ker,
                                               const float* __restrict__ feat,
                                               float* __restrict__ out,
                                               float* __restrict__ cisT,
                                               unsigned long long* __restrict__ slots) {
  __shared__ __align__(16) float histT[GT][132];   // [token][t], 67.6 KB
  __shared__ __align__(16) float colbuf[TOPK];
  __shared__ unsigned long long redw[GT / 64];
  __shared__ unsigned long long bwS;
  __shared__ int selj[TOPK];
  int tid = threadIdx.x;
  int lane = tid & 63, wid = tid >> 6;
  int blk = blockIdx.x;
  int n = blk * GT + tid;
  float di2s = ker[(size_t)n * NTOK + n];
#pragma unroll
  for (int t = 0; t < TOPK; t += 4)
    *(float4*)&histT[tid][t] = (float4){0.f, 0.f, 0.f, 0.f};

  for (int i = 0; i < TOPK; ++i) {
    unsigned u = __float_as_uint(di2s);
    unsigned key = (u & 0x80000000u) ? ~u : (u | 0x80000000u);
    unsigned long long pk =
        ((unsigned long long)key << 32) | (unsigned)(NTOK - 1 - n);
    for (int o = 32; o >= 1; o >>= 1) {
      unsigned long long q = __shfl_down(pk, o, 64);
      if (q > pk) pk = q;
    }
    if (lane == 0) redw[wid] = pk;
    __syncthreads();   // B1: orders redw + drains iter-(i-1) cisT stores
    if (tid == 0) {
      unsigned long long m = redw[0];
      if (redw[1] > m) m = redw[1];
      __hip_atomic_store(&slots[((size_t)i * GB + blk) * 8], m,
                         __ATOMIC_RELEASE, __HIP_MEMORY_SCOPE_AGENT);
    }
    if (wid == 0) {
      unsigned long long v = 0;
      if (lane < GB) {
        do {
          v = __hip_atomic_load(&slots[((size_t)i * GB + lane) * 8],
                                __ATOMIC_RELAXED, __HIP_MEMORY_SCOPE_AGENT);
        } while (v == 0);
      }
      unsigned long long b1 = v;
      for (int o = 32; o >= 1; o >>= 1) {
        unsigned long long q = __shfl_down(b1, o, 64);
        if (q > b1) b1 = q;
      }
      b1 = __shfl(b1, 0, 64);
      int jw = NTOK - 1 - (int)(b1 & 0xffffffffu);
      // winner history column: contiguous cisT[jw][0..127], 64 lanes x 8B
      // agent-relaxed atomic loads (coherence point; address data-dependent
      // on the polled slot values -> ordered behind the poll).
      unsigned long long cu = __hip_atomic_load(
          (const unsigned long long*)(cisT + (size_t)jw * TOPK) + lane,
          __ATOMIC_RELAXED, __HIP_MEMORY_SCOPE_AGENT);
      union { unsigned long long u64; float f[2]; } cc; cc.u64 = cu;
      colbuf[lane * 2]     = cc.f[0];
      colbuf[lane * 2 + 1] = cc.f[1];
      if (lane == 0) bwS = b1;
    }
    __syncthreads();   // B2: colbuf + bwS published block-wide
    unsigned long long b1 = bwS;
    int j = NTOK - 1 - (int)(b1 & 0xffffffffu);
    unsigned kw = (unsigned)(b1 >> 32);
    unsigned du = (kw & 0x80000000u) ? (kw & 0x7fffffffu) : ~kw;
    float sd = sqrtf(__uint_as_float(du));
    if (tid == 0) selj[i] = j;
    float kj = ker[(size_t)j * NTOK + n];
    float proj = 0.f;
    for (int t = 0; t < i; t += 4) {
      float4 c4 = *(const float4*)&colbuf[t];
      float4 h4 = *(const float4*)&histT[tid][t];
      proj += c4.x * h4.x + c4.y * h4.y + c4.z * h4.z + c4.w * h4.w;
    }
    float eis = (kj - proj) / sd;
    __hip_atomic_store(&cisT[(size_t)n * TOPK + i], eis, __ATOMIC_RELAXED,
                       __HIP_MEMORY_SCOPE_AGENT);
    histT[tid][i] = eis;
    di2s -= eis * eis;
    if (n == j) di2s = NEGM;
  }
  __syncthreads();
  for (int k = blk; k < TOPK; k += GB) {
    int j = selj[k];
    const float4* src = (const float4*)(feat + (size_t)j * DIM);
    float4* dst = (float4*)(out + (size_t)k * DIM);
    dst[tid]       = src[tid];
    dst[tid + GT]  = src[tid + GT];
  }
}

// ---------------------------------------------------------------------------
// ws layout (bytes):
//   [0,262144)        slots: 128 iters x 32 blocks x 64B (zeroed each launch)
//   [262144,278528)   rel  : 4096 f32
//   [1MB, +8MB)       H    : 4096x1024 bf16
//   [1MB+8MB, +8MB)   L    : 4096x1024 bf16
//   [1MB+16MB, +2MB)  cisT : 4096x128 f32  (layout [token][t])
//   [1MB+20MB, +64MB) ker  : 4096x4096 f32
// total ~85 MB
// ---------------------------------------------------------------------------
extern "C" void kernel_launch(void* const* d_in, const int* in_sizes, int n_in,
                              void* d_out, int out_size, void* d_ws, size_t ws_size,
                              hipStream_t stream) {
  const float* feat = (const float*)d_in[0];
  const float* attn = (const float*)d_in[1];
  float* out = (float*)d_out;
  char* ws = (char*)d_ws;

  unsigned long long* slots = (unsigned long long*)ws;
  float* rel = (float*)(ws + 262144);
  __hip_bfloat16* H = (__hip_bfloat16*)(ws + (1 << 20));
  __hip_bfloat16* L = (__hip_bfloat16*)(ws + (1 << 20) + (8 << 20));
  float* cisT = (float*)(ws + (1 << 20) + (16 << 20));
  float* ker  = (float*)(ws + (1 << 20) + (16 << 20) + (4 << 20));

  hipMemsetAsync(d_ws, 0, 262144, stream);
  k_prep<<<1, 1024, 0, stream>>>(attn, rel);
  k_norm<<<NTOK, 256, 0, stream>>>(feat, H, L);
  k_gemm<<<dim3(32, 32), 256, 0, stream>>>(H, L, rel, ker);
  k_greedy<<<GB, GT, 0, stream>>>(ker, feat, out, cisT, slots);
}